// Round 1
// baseline (45.771 us; speedup 1.0000x reference)
//
#include <hip/hip_runtime.h>

#define HWD (512 * 512)   // pixels per image
#define NCLS 8
#define NBATCH 16
#define MAIN_GX 128       // blocks per image in main kernel
#define MAIN_BLK 256

// 64-lane wave reductions
#define WRED_I(x) { x += __shfl_down(x, 32); x += __shfl_down(x, 16); x += __shfl_down(x, 8); \
                    x += __shfl_down(x, 4);  x += __shfl_down(x, 2);  x += __shfl_down(x, 1); }
#define WRED_F(x) { x += __shfl_down(x, 32); x += __shfl_down(x, 16); x += __shfl_down(x, 8); \
                    x += __shfl_down(x, 4);  x += __shfl_down(x, 2);  x += __shfl_down(x, 1); }

// ---------------- Kernel 1: class histogram over the whole target tensor ----------------
__global__ void __launch_bounds__(256) wce_hist(const int* __restrict__ target,
                                                int* __restrict__ counts) {
    const int total4 = (NBATCH * HWD) / 4;
    int tid = blockIdx.x * blockDim.x + threadIdx.x;
    int stride = gridDim.x * blockDim.x;
    int c0 = 0, c1 = 0, c2 = 0, c3 = 0, c4 = 0, c5 = 0, c6 = 0, c7 = 0;
    const int4* t4 = (const int4*)target;
    for (int i = tid; i < total4; i += stride) {
        int4 v = t4[i];
#define ACC(X) { int a = min(max((X), 0), 7); \
                 c0 += (a == 0); c1 += (a == 1); c2 += (a == 2); c3 += (a == 3); \
                 c4 += (a == 4); c5 += (a == 5); c6 += (a == 6); c7 += (a == 7); }
        ACC(v.x) ACC(v.y) ACC(v.z) ACC(v.w)
#undef ACC
    }
    WRED_I(c0) WRED_I(c1) WRED_I(c2) WRED_I(c3)
    WRED_I(c4) WRED_I(c5) WRED_I(c6) WRED_I(c7)
    __shared__ int sb[8];
    if (threadIdx.x < 8) sb[threadIdx.x] = 0;
    __syncthreads();
    if ((threadIdx.x & 63) == 0) {
        atomicAdd(&sb[0], c0); atomicAdd(&sb[1], c1);
        atomicAdd(&sb[2], c2); atomicAdd(&sb[3], c3);
        atomicAdd(&sb[4], c4); atomicAdd(&sb[5], c5);
        atomicAdd(&sb[6], c6); atomicAdd(&sb[7], c7);
    }
    __syncthreads();
    if (threadIdx.x < 8) atomicAdd(&counts[threadIdx.x], sb[threadIdx.x]);
}

// ---------------- Kernel 2: per-pixel log-softmax gather + weighted partial sums ----------------
__global__ void __launch_bounds__(MAIN_BLK) wce_main(const float* __restrict__ pred,
                                                     const int* __restrict__ target,
                                                     const int* __restrict__ counts,
                                                     float* __restrict__ pnum,
                                                     float* __restrict__ pden) {
    const int n = blockIdx.y;
    __shared__ float wtab[8];
    if (threadIdx.x < 8)
        wtab[threadIdx.x] = 1.0f / ((float)counts[threadIdx.x] + 1e-6f);
    __syncthreads();

    const float* p = pred + (size_t)n * NCLS * HWD;
    const int4* tg4 = (const int4*)(target + (size_t)n * HWD);

    float snum = 0.0f, sden = 0.0f;
    int tid = blockIdx.x * blockDim.x + threadIdx.x;
    const int stride = MAIN_GX * MAIN_BLK;
    for (int i = tid; i < HWD / 4; i += stride) {
        int4 t4 = tg4[i];
        float4 l0 = ((const float4*)(p + 0 * HWD))[i];
        float4 l1 = ((const float4*)(p + 1 * HWD))[i];
        float4 l2 = ((const float4*)(p + 2 * HWD))[i];
        float4 l3 = ((const float4*)(p + 3 * HWD))[i];
        float4 l4 = ((const float4*)(p + 4 * HWD))[i];
        float4 l5 = ((const float4*)(p + 5 * HWD))[i];
        float4 l6 = ((const float4*)(p + 6 * HWD))[i];
        float4 l7 = ((const float4*)(p + 7 * HWD))[i];
#define PIX(F, T) { \
        int t = min(max((T), 0), 7); \
        float a0 = l0.F, a1 = l1.F, a2 = l2.F, a3 = l3.F; \
        float a4 = l4.F, a5 = l5.F, a6 = l6.F, a7 = l7.F; \
        float m = fmaxf(fmaxf(fmaxf(a0, a1), fmaxf(a2, a3)), \
                        fmaxf(fmaxf(a4, a5), fmaxf(a6, a7))); \
        float s = __expf(a0 - m) + __expf(a1 - m) + __expf(a2 - m) + __expf(a3 - m) + \
                  __expf(a4 - m) + __expf(a5 - m) + __expf(a6 - m) + __expf(a7 - m); \
        float at = t == 0 ? a0 : t == 1 ? a1 : t == 2 ? a2 : t == 3 ? a3 : \
                   t == 4 ? a4 : t == 5 ? a5 : t == 6 ? a6 : a7; \
        float lp = at - m - __logf(s); \
        float wgt = wtab[t]; \
        snum += lp * wgt; sden += wgt; }
        PIX(x, t4.x) PIX(y, t4.y) PIX(z, t4.z) PIX(w, t4.w)
#undef PIX
    }

    WRED_F(snum) WRED_F(sden)
    __shared__ float sn[MAIN_BLK / 64], sd[MAIN_BLK / 64];
    const int wave = threadIdx.x >> 6;
    if ((threadIdx.x & 63) == 0) { sn[wave] = snum; sd[wave] = sden; }
    __syncthreads();
    if (threadIdx.x == 0) {
        float a = sn[0] + sn[1] + sn[2] + sn[3];
        float b = sd[0] + sd[1] + sd[2] + sd[3];
        pnum[n * MAIN_GX + blockIdx.x] = a;
        pden[n * MAIN_GX + blockIdx.x] = b;
    }
}

// ---------------- Kernel 3: finalize -mean(num/den) ----------------
__global__ void __launch_bounds__(1024) wce_final(const float* __restrict__ pnum,
                                                  const float* __restrict__ pden,
                                                  float* __restrict__ out) {
    const int wave = threadIdx.x >> 6;   // wave w handles image n = w (16 waves)
    const int lane = threadIdx.x & 63;
    float a = pnum[wave * MAIN_GX + lane] + pnum[wave * MAIN_GX + lane + 64];
    float b = pden[wave * MAIN_GX + lane] + pden[wave * MAIN_GX + lane + 64];
    WRED_F(a) WRED_F(b)
    __shared__ float r[16];
    if (lane == 0) r[wave] = a / b;
    __syncthreads();
    if (threadIdx.x == 0) {
        float s = 0.0f;
        for (int k = 0; k < 16; ++k) s += r[k];
        out[0] = -s / 16.0f;
    }
}

extern "C" void kernel_launch(void* const* d_in, const int* in_sizes, int n_in,
                              void* d_out, int out_size, void* d_ws, size_t ws_size,
                              hipStream_t stream) {
    const float* pred = (const float*)d_in[0];
    const int* target = (const int*)d_in[1];

    // ws layout: [0..7] int counts | [8 .. 8+2048) float partial num | then partial den
    int* counts = (int*)d_ws;
    float* pnum = (float*)d_ws + 8;
    float* pden = pnum + NBATCH * MAIN_GX;

    hipMemsetAsync(d_ws, 0, 8 * sizeof(int), stream);  // zero counts each call
    hipLaunchKernelGGL(wce_hist, dim3(512), dim3(256), 0, stream, target, counts);
    hipLaunchKernelGGL(wce_main, dim3(MAIN_GX, NBATCH), dim3(MAIN_BLK), 0, stream,
                       pred, target, counts, pnum, pden);
    hipLaunchKernelGGL(wce_final, dim3(1), dim3(1024), 0, stream, pnum, pden, (float*)d_out);
}

// Round 2
// 34.878 us; speedup vs baseline: 1.3123x; 1.3123x over previous
//
#include <hip/hip_runtime.h>

#define HWD (512 * 512)   // pixels per image
#define NCLS 8
#define NBATCH 16
#define MAIN_GX 128       // blocks per image in main kernel
#define MAIN_BLK 256
#define NBLK (NBATCH * MAIN_GX)   // 2048 total blocks

// 64-lane wave reductions
#define WRED(x) { x += __shfl_down(x, 32); x += __shfl_down(x, 16); x += __shfl_down(x, 8); \
                  x += __shfl_down(x, 4);  x += __shfl_down(x, 2);  x += __shfl_down(x, 1); }

// ---------------- Kernel 1: log-softmax gather, per-class partial sums + counts ----------------
// Weight factorization: num_n = sum_c w_c * S[n][c], den_n = sum_c w_c * K[n][c],
// where S = per-class lp-sums and K = per-class pixel counts. No global histogram
// needed here -> single pass over pred and target.
__global__ void __launch_bounds__(MAIN_BLK) wce_main(const float* __restrict__ pred,
                                                     const int* __restrict__ target,
                                                     float* __restrict__ pS,   // [c][n][bx]
                                                     int* __restrict__ pC) {   // [c][n][bx]
    const int n = blockIdx.y;
    const int bx = blockIdx.x;
    const float* p = pred + (size_t)n * NCLS * HWD;
    const int4* tg4 = (const int4*)(target + (size_t)n * HWD);

    float s0 = 0, s1 = 0, s2 = 0, s3 = 0, s4 = 0, s5 = 0, s6 = 0, s7 = 0;
    int   k0 = 0, k1 = 0, k2 = 0, k3 = 0, k4 = 0, k5 = 0, k6 = 0, k7 = 0;

    int tid = bx * MAIN_BLK + threadIdx.x;
    const int stride = MAIN_GX * MAIN_BLK;
    for (int i = tid; i < HWD / 4; i += stride) {
        int4 t4 = tg4[i];
        float4 l0 = ((const float4*)(p + 0 * HWD))[i];
        float4 l1 = ((const float4*)(p + 1 * HWD))[i];
        float4 l2 = ((const float4*)(p + 2 * HWD))[i];
        float4 l3 = ((const float4*)(p + 3 * HWD))[i];
        float4 l4 = ((const float4*)(p + 4 * HWD))[i];
        float4 l5 = ((const float4*)(p + 5 * HWD))[i];
        float4 l6 = ((const float4*)(p + 6 * HWD))[i];
        float4 l7 = ((const float4*)(p + 7 * HWD))[i];
#define PIX(F, T) { \
        int t = min(max((T), 0), 7); \
        float a0 = l0.F, a1 = l1.F, a2 = l2.F, a3 = l3.F; \
        float a4 = l4.F, a5 = l5.F, a6 = l6.F, a7 = l7.F; \
        float m = fmaxf(fmaxf(fmaxf(a0, a1), fmaxf(a2, a3)), \
                        fmaxf(fmaxf(a4, a5), fmaxf(a6, a7))); \
        float s = __expf(a0 - m) + __expf(a1 - m) + __expf(a2 - m) + __expf(a3 - m) + \
                  __expf(a4 - m) + __expf(a5 - m) + __expf(a6 - m) + __expf(a7 - m); \
        float at = t == 0 ? a0 : t == 1 ? a1 : t == 2 ? a2 : t == 3 ? a3 : \
                   t == 4 ? a4 : t == 5 ? a5 : t == 6 ? a6 : a7; \
        float lp = at - m - __logf(s); \
        s0 += (t == 0) ? lp : 0.0f; s1 += (t == 1) ? lp : 0.0f; \
        s2 += (t == 2) ? lp : 0.0f; s3 += (t == 3) ? lp : 0.0f; \
        s4 += (t == 4) ? lp : 0.0f; s5 += (t == 5) ? lp : 0.0f; \
        s6 += (t == 6) ? lp : 0.0f; s7 += (t == 7) ? lp : 0.0f; \
        k0 += (t == 0); k1 += (t == 1); k2 += (t == 2); k3 += (t == 3); \
        k4 += (t == 4); k5 += (t == 5); k6 += (t == 6); k7 += (t == 7); }
        PIX(x, t4.x) PIX(y, t4.y) PIX(z, t4.z) PIX(w, t4.w)
#undef PIX
    }

    WRED(s0) WRED(s1) WRED(s2) WRED(s3) WRED(s4) WRED(s5) WRED(s6) WRED(s7)
    WRED(k0) WRED(k1) WRED(k2) WRED(k3) WRED(k4) WRED(k5) WRED(k6) WRED(k7)

    __shared__ float ls[MAIN_BLK / 64][8];
    __shared__ int   li[MAIN_BLK / 64][8];
    const int wave = threadIdx.x >> 6;
    if ((threadIdx.x & 63) == 0) {
        ls[wave][0] = s0; ls[wave][1] = s1; ls[wave][2] = s2; ls[wave][3] = s3;
        ls[wave][4] = s4; ls[wave][5] = s5; ls[wave][6] = s6; ls[wave][7] = s7;
        li[wave][0] = k0; li[wave][1] = k1; li[wave][2] = k2; li[wave][3] = k3;
        li[wave][4] = k4; li[wave][5] = k5; li[wave][6] = k6; li[wave][7] = k7;
    }
    __syncthreads();
    if (threadIdx.x < 8) {
        int c = threadIdx.x;
        float v = ls[0][c] + ls[1][c] + ls[2][c] + ls[3][c];
        pS[c * NBLK + n * MAIN_GX + bx] = v;
    } else if (threadIdx.x < 16) {
        int c = threadIdx.x - 8;
        int v = li[0][c] + li[1][c] + li[2][c] + li[3][c];
        pC[c * NBLK + n * MAIN_GX + bx] = v;
    }
}

// ---------------- Kernel 2: global histogram from per-block counts, weights, final loss ----------------
__global__ void __launch_bounds__(1024) wce_final(const float* __restrict__ pS,
                                                  const int* __restrict__ pC,
                                                  float* __restrict__ out) {
    const int wave = threadIdx.x >> 6;  // 16 waves
    const int lane = threadIdx.x & 63;
    __shared__ float gc[16];
    __shared__ float wtab[8];
    __shared__ float r[16];

    // Phase A: global class counts. wave w -> class c = w>>1, half h = w&1 (1024 ints each).
    {
        const int c = wave >> 1, h = wave & 1;
        const int* base = pC + c * NBLK + h * (NBLK / 2);
        int acc = 0;
#pragma unroll
        for (int k = 0; k < NBLK / 2 / 64; ++k) acc += base[lane + k * 64];
        WRED(acc)
        if (lane == 0) gc[wave] = (float)acc;
    }
    __syncthreads();
    if (threadIdx.x < 8)
        wtab[threadIdx.x] = 1.0f / (gc[2 * threadIdx.x] + gc[2 * threadIdx.x + 1] + 1e-6f);
    __syncthreads();

    // Phase B: wave w = image n. num/den via weighted per-class partials.
    {
        const int n = wave;
        float num = 0.0f, den = 0.0f;
#pragma unroll
        for (int c = 0; c < 8; ++c) {
            const float* sb = pS + c * NBLK + n * MAIN_GX;
            const int*   cb = pC + c * NBLK + n * MAIN_GX;
            float sv = sb[lane] + sb[lane + 64];
            float cv = (float)(cb[lane] + cb[lane + 64]);
            float w = wtab[c];
            num += w * sv;
            den += w * cv;
        }
        WRED(num) WRED(den)
        if (lane == 0) r[n] = num / den;
    }
    __syncthreads();
    if (threadIdx.x == 0) {
        float s = 0.0f;
#pragma unroll
        for (int k = 0; k < 16; ++k) s += r[k];
        out[0] = -s / 16.0f;
    }
}

extern "C" void kernel_launch(void* const* d_in, const int* in_sizes, int n_in,
                              void* d_out, int out_size, void* d_ws, size_t ws_size,
                              hipStream_t stream) {
    const float* pred = (const float*)d_in[0];
    const int* target = (const int*)d_in[1];

    // ws layout: pS [8][2048] floats | pC [8][2048] ints (every slot written by wce_main)
    float* pS = (float*)d_ws;
    int* pC = (int*)(pS + NCLS * NBLK);

    hipLaunchKernelGGL(wce_main, dim3(MAIN_GX, NBATCH), dim3(MAIN_BLK), 0, stream,
                       pred, target, pS, pC);
    hipLaunchKernelGGL(wce_final, dim3(1), dim3(1024), 0, stream, pS, pC, (float*)d_out);
}